// Round 2
// baseline (63.758 us; speedup 1.0000x reference)
//
#include <hip/hip_runtime.h>

#define BATCH 128
#define DVAR  64
#define HDIM  128

// Grid: 256 blocks = (batch b = blockIdx>>1, i-half = blockIdx&1), 256 threads.
// Thread mapping for all matmul-ish phases: k = tid&127 (output column),
// grp = tid>>7 (row-group). Waves are grp-uniform -> LDS row reads broadcast.
__global__ __launch_bounds__(256, 1) void gnn_fused(
    const float* __restrict__ X,      // (B,D)
    const float* __restrict__ W,      // (D,D)
    const float* __restrict__ enc_w,  // (1,H)
    const float* __restrict__ enc_b,  // (H)
    const float* __restrict__ mw1,    // (2H,H)
    const float* __restrict__ mb1,    // (H)
    const float* __restrict__ mw2,    // (H,H)
    const float* __restrict__ mb2,    // (H)
    const float* __restrict__ dw1,    // (2H,H)
    const float* __restrict__ db1,    // (H)
    const float* __restrict__ dw2,    // (H,1)
    const float* __restrict__ db2,    // (1)
    float* __restrict__ out)          // (B,D)
{
    __shared__ float h_lds[DVAR][HDIM];   // 32 KB, h for all 64 rows
    __shared__ float u_lds[DVAR][HDIM];   // 32 KB; rows 0..31 reused as agg later
    __shared__ float r_lds[32][HDIM];     // 16 KB; reused as z later
    __shared__ float A_lds[DVAR][32];     // 8 KB: A[j][ii], ii local i
    __shared__ float Asum_lds[32];

    const int tid = threadIdx.x;
    const int b   = blockIdx.x >> 1;
    const int i0  = (blockIdx.x & 1) * 32;   // this block's global i range: [i0, i0+32)
    const int k   = tid & (HDIM - 1);
    const int grp = tid >> 7;                // 0 or 1 (wave-uniform)

    // ---- Phase 1: h[j][k] = tanh(X[b,j]*enc_w[k] + enc_b[k]); stage masked A column-slab ----
    {
        const float ew = enc_w[k];
        const float eb = enc_b[k];
        #pragma unroll
        for (int m = 0; m < 32; ++m) {
            const int j = (tid >> 7) + m * 2;          // (tid + m*256)>>7, col stays k
            h_lds[j][k] = tanhf(X[b * DVAR + j] * ew + eb);
        }
        #pragma unroll
        for (int m = 0; m < 8; ++m) {
            const int idx = tid + m * 256;
            const int j = idx >> 5, ii = idx & 31;
            const int i = i0 + ii;
            A_lds[j][ii] = (j == i) ? 0.0f : W[j * DVAR + i];
        }
    }
    __syncthreads();
    if (tid < 32) {                                    // Asum[ii] = sum_j A[j,i]
        float s = 0.0f;
        for (int j = 0; j < DVAR; ++j) s += A_lds[j][tid];
        Asum_lds[tid] = s;
    }
    __syncthreads();

    // ---- Phase 2a: u[j][k] = sum_t h[j][t] * mw1[t][k], all 64 rows (32 per grp) ----
    {
        float acc[32];
        #pragma unroll
        for (int j = 0; j < 32; ++j) acc[j] = 0.0f;
        const int j0 = grp * 32;
        for (int t = 0; t < HDIM; t += 4) {
            const float w0 = mw1[(t + 0) * HDIM + k];
            const float w1 = mw1[(t + 1) * HDIM + k];
            const float w2 = mw1[(t + 2) * HDIM + k];
            const float w3 = mw1[(t + 3) * HDIM + k];
            #pragma unroll
            for (int j = 0; j < 32; ++j) {
                const float4 hv = *(const float4*)&h_lds[j0 + j][t];
                acc[j] = fmaf(hv.x, w0, acc[j]);
                acc[j] = fmaf(hv.y, w1, acc[j]);
                acc[j] = fmaf(hv.z, w2, acc[j]);
                acc[j] = fmaf(hv.w, w3, acc[j]);
            }
        }
        #pragma unroll
        for (int j = 0; j < 32; ++j) u_lds[j0 + j][k] = acc[j];
    }

    // ---- Phase 2b: vv[ii] = (h[i0+grp*16+ii] @ mw1[H:])[k] + mb1[k], kept in registers ----
    float vv[16];
    {
        float acc[16];
        #pragma unroll
        for (int ii = 0; ii < 16; ++ii) acc[ii] = 0.0f;
        const int r0 = i0 + grp * 16;
        for (int t = 0; t < HDIM; t += 4) {
            const float w0 = mw1[(HDIM + t + 0) * HDIM + k];
            const float w1 = mw1[(HDIM + t + 1) * HDIM + k];
            const float w2 = mw1[(HDIM + t + 2) * HDIM + k];
            const float w3 = mw1[(HDIM + t + 3) * HDIM + k];
            #pragma unroll
            for (int ii = 0; ii < 16; ++ii) {
                const float4 hv = *(const float4*)&h_lds[r0 + ii][t];
                acc[ii] = fmaf(hv.x, w0, acc[ii]);
                acc[ii] = fmaf(hv.y, w1, acc[ii]);
                acc[ii] = fmaf(hv.z, w2, acc[ii]);
                acc[ii] = fmaf(hv.w, w3, acc[ii]);
            }
        }
        const float bk = mb1[k];
        #pragma unroll
        for (int ii = 0; ii < 16; ++ii) vv[ii] = acc[ii] + bk;
    }
    __syncthreads();   // publish u_lds

    // ---- Phase 3: r[i_loc][k] = sum_j A[j][i_loc] * relu(u[j][k] + vv[i_loc]) ----
    {
        float racc[16];
        #pragma unroll
        for (int ii = 0; ii < 16; ++ii) racc[ii] = 0.0f;
        for (int j = 0; j < DVAR; ++j) {
            const float uv = u_lds[j][k];
            const float4* arow = (const float4*)&A_lds[j][grp * 16];
            const float4 a0 = arow[0], a1 = arow[1], a2 = arow[2], a3 = arow[3];
            float av[16];
            av[0]=a0.x; av[1]=a0.y; av[2]=a0.z;  av[3]=a0.w;
            av[4]=a1.x; av[5]=a1.y; av[6]=a1.z;  av[7]=a1.w;
            av[8]=a2.x; av[9]=a2.y; av[10]=a2.z; av[11]=a2.w;
            av[12]=a3.x; av[13]=a3.y; av[14]=a3.z; av[15]=a3.w;
            #pragma unroll
            for (int ii = 0; ii < 16; ++ii) {
                const float p = fmaxf(uv + vv[ii], 0.0f);
                racc[ii] = fmaf(p, av[ii], racc[ii]);
            }
        }
        #pragma unroll
        for (int ii = 0; ii < 16; ++ii) r_lds[grp * 16 + ii][k] = racc[ii];
    }
    __syncthreads();   // publish r_lds; all u_lds reads done -> rows 0..31 reusable as agg

    // ---- Phase 4: agg[ii][k] = r[ii] @ mw2[:,k] + Asum[ii]*mb2[k]  (into u_lds rows 0..31) ----
    {
        float acc[16];
        #pragma unroll
        for (int ii = 0; ii < 16; ++ii) acc[ii] = 0.0f;
        for (int t = 0; t < HDIM; t += 4) {
            const float w0 = mw2[(t + 0) * HDIM + k];
            const float w1 = mw2[(t + 1) * HDIM + k];
            const float w2 = mw2[(t + 2) * HDIM + k];
            const float w3 = mw2[(t + 3) * HDIM + k];
            #pragma unroll
            for (int ii = 0; ii < 16; ++ii) {
                const float4 rv = *(const float4*)&r_lds[grp * 16 + ii][t];
                acc[ii] = fmaf(rv.x, w0, acc[ii]);
                acc[ii] = fmaf(rv.y, w1, acc[ii]);
                acc[ii] = fmaf(rv.z, w2, acc[ii]);
                acc[ii] = fmaf(rv.w, w3, acc[ii]);
            }
        }
        const float b2 = mb2[k];
        #pragma unroll
        for (int ii = 0; ii < 16; ++ii)
            u_lds[grp * 16 + ii][k] = acc[ii] + Asum_lds[grp * 16 + ii] * b2;  // agg
    }
    __syncthreads();   // publish agg; all r_lds reads done -> reusable as z

    // ---- Phase 5: z[ii][k] = relu(h[i0+ii]@dw1[:H,k] + agg[ii]@dw1[H:,k] + db1[k]) ----
    {
        float acc[16];
        #pragma unroll
        for (int ii = 0; ii < 16; ++ii) acc[ii] = 0.0f;
        const int hrow0 = i0 + grp * 16;
        for (int t = 0; t < HDIM; t += 4) {
            const float w0 = dw1[(t + 0) * HDIM + k];
            const float w1 = dw1[(t + 1) * HDIM + k];
            const float w2 = dw1[(t + 2) * HDIM + k];
            const float w3 = dw1[(t + 3) * HDIM + k];
            #pragma unroll
            for (int ii = 0; ii < 16; ++ii) {
                const float4 hv = *(const float4*)&h_lds[hrow0 + ii][t];
                acc[ii] = fmaf(hv.x, w0, acc[ii]);
                acc[ii] = fmaf(hv.y, w1, acc[ii]);
                acc[ii] = fmaf(hv.z, w2, acc[ii]);
                acc[ii] = fmaf(hv.w, w3, acc[ii]);
            }
        }
        for (int t = 0; t < HDIM; t += 4) {
            const float w0 = dw1[(HDIM + t + 0) * HDIM + k];
            const float w1 = dw1[(HDIM + t + 1) * HDIM + k];
            const float w2 = dw1[(HDIM + t + 2) * HDIM + k];
            const float w3 = dw1[(HDIM + t + 3) * HDIM + k];
            #pragma unroll
            for (int ii = 0; ii < 16; ++ii) {
                const float4 av = *(const float4*)&u_lds[grp * 16 + ii][t];   // agg
                acc[ii] = fmaf(av.x, w0, acc[ii]);
                acc[ii] = fmaf(av.y, w1, acc[ii]);
                acc[ii] = fmaf(av.z, w2, acc[ii]);
                acc[ii] = fmaf(av.w, w3, acc[ii]);
            }
        }
        const float bk = db1[k];
        #pragma unroll
        for (int ii = 0; ii < 16; ++ii)
            r_lds[grp * 16 + ii][k] = fmaxf(acc[ii] + bk, 0.0f);   // z
    }
    __syncthreads();

    // ---- Phase 6: out[b][i0+row] = z[row] @ dw2 + db2 ----
    {
        const int row = tid >> 3;      // 0..31
        const int s   = tid & 7;
        float part = 0.0f;
        #pragma unroll
        for (int m = 0; m < 16; ++m) {
            const int kk = s + m * 8;
            part += r_lds[row][kk] * dw2[kk];
        }
        part += __shfl_xor(part, 1);
        part += __shfl_xor(part, 2);
        part += __shfl_xor(part, 4);
        if (s == 0) out[b * DVAR + i0 + row] = part + db2[0];
    }
}

extern "C" void kernel_launch(void* const* d_in, const int* in_sizes, int n_in,
                              void* d_out, int out_size, void* d_ws, size_t ws_size,
                              hipStream_t stream) {
    const float* X     = (const float*)d_in[0];
    const float* W     = (const float*)d_in[1];
    const float* enc_w = (const float*)d_in[2];
    const float* enc_b = (const float*)d_in[3];
    const float* mw1   = (const float*)d_in[4];
    const float* mb1   = (const float*)d_in[5];
    const float* mw2   = (const float*)d_in[6];
    const float* mb2   = (const float*)d_in[7];
    const float* dw1   = (const float*)d_in[8];
    const float* db1   = (const float*)d_in[9];
    const float* dw2   = (const float*)d_in[10];
    const float* db2   = (const float*)d_in[11];

    gnn_fused<<<dim3(BATCH * 2), dim3(256), 0, stream>>>(
        X, W, enc_w, enc_b, mw1, mb1, mw2, mb2, dw1, db1, dw2, db2,
        (float*)d_out);
}

// Round 3
// 47.892 us; speedup vs baseline: 1.3313x; 1.3313x over previous
//
#include <hip/hip_runtime.h>

#define BATCH 128
#define DVAR  64
#define HDIM  128
#define NT    1024   // 16 waves/block, 4 waves/SIMD at 1 block/CU

// Grid: 256 blocks = (batch b = blockIdx>>1, i-half = blockIdx&1), 1024 threads.
// Thread mapping: k = tid&127 (output column), grp = tid>>7 (0..7, wave-uniform).
// Each grp owns 8 j-rows (phase 2a) / 4 i-rows (phases 2b..5).
__global__ __launch_bounds__(NT, 1) void gnn_fused(
    const float* __restrict__ X,      // (B,D)
    const float* __restrict__ W,      // (D,D)
    const float* __restrict__ enc_w,  // (1,H)
    const float* __restrict__ enc_b,  // (H)
    const float* __restrict__ mw1,    // (2H,H)
    const float* __restrict__ mb1,    // (H)
    const float* __restrict__ mw2,    // (H,H)
    const float* __restrict__ mb2,    // (H)
    const float* __restrict__ dw1,    // (2H,H)
    const float* __restrict__ db1,    // (H)
    const float* __restrict__ dw2,    // (H,1)
    const float* __restrict__ db2,    // (1)
    float* __restrict__ out)          // (B,D)
{
    __shared__ float h_lds[DVAR][HDIM];   // 32 KB
    __shared__ float u_lds[DVAR][HDIM];   // 32 KB; rows 0..31 reused as agg
    __shared__ float r_lds[32][HDIM];     // 16 KB; reused as z
    __shared__ float A_lds[DVAR][32];     // 8 KB
    __shared__ float Asum_lds[32];

    const int tid = threadIdx.x;
    const int b   = blockIdx.x >> 1;
    const int i0  = (blockIdx.x & 1) * 32;   // global i range [i0, i0+32)
    const int k   = tid & (HDIM - 1);
    const int grp = tid >> 7;                // 0..7, wave-uniform

    // ---- Phase 1: h[j][k] = tanh(X[b,j]*enc_w[k]+enc_b[k]); stage masked A slab ----
    {
        const float ew = enc_w[k];
        const float eb = enc_b[k];
        #pragma unroll
        for (int m = 0; m < 8; ++m) {
            const int j = grp + m * 8;                 // wave-uniform row
            h_lds[j][k] = tanhf(X[b * DVAR + j] * ew + eb);
        }
        #pragma unroll
        for (int m = 0; m < 2; ++m) {
            const int idx = tid + m * NT;              // 0..2047
            const int j = idx >> 5, ii = idx & 31;
            A_lds[j][ii] = (j == i0 + ii) ? 0.0f : W[j * DVAR + i0 + ii];
        }
    }
    __syncthreads();
    if (tid < 32) {                                    // Asum[ii] = sum_j A[j,i]
        float s = 0.0f;
        for (int j = 0; j < DVAR; ++j) s += A_lds[j][tid];
        Asum_lds[tid] = s;
    }

    // ---- Phase 2a: u[j][k] = h[j] @ mw1[:H][:,k], 8 rows per grp ----
    {
        float acc[8];
        #pragma unroll
        for (int j = 0; j < 8; ++j) acc[j] = 0.0f;
        const int j0 = grp * 8;
        #pragma unroll 4
        for (int t = 0; t < HDIM; t += 4) {
            const float w0 = mw1[(t + 0) * HDIM + k];
            const float w1 = mw1[(t + 1) * HDIM + k];
            const float w2 = mw1[(t + 2) * HDIM + k];
            const float w3 = mw1[(t + 3) * HDIM + k];
            #pragma unroll
            for (int j = 0; j < 8; ++j) {
                const float4 hv = *(const float4*)&h_lds[j0 + j][t];
                acc[j] = fmaf(hv.x, w0, acc[j]);
                acc[j] = fmaf(hv.y, w1, acc[j]);
                acc[j] = fmaf(hv.z, w2, acc[j]);
                acc[j] = fmaf(hv.w, w3, acc[j]);
            }
        }
        #pragma unroll
        for (int j = 0; j < 8; ++j) u_lds[j0 + j][k] = acc[j];
    }

    // ---- Phase 2b: vv[ii] = (h[i0+grp*4+ii] @ mw1[H:])[k] + mb1[k], in registers ----
    float vv[4];
    {
        float acc[4];
        #pragma unroll
        for (int ii = 0; ii < 4; ++ii) acc[ii] = 0.0f;
        const int r0 = i0 + grp * 4;
        #pragma unroll 4
        for (int t = 0; t < HDIM; t += 4) {
            const float w0 = mw1[(HDIM + t + 0) * HDIM + k];
            const float w1 = mw1[(HDIM + t + 1) * HDIM + k];
            const float w2 = mw1[(HDIM + t + 2) * HDIM + k];
            const float w3 = mw1[(HDIM + t + 3) * HDIM + k];
            #pragma unroll
            for (int ii = 0; ii < 4; ++ii) {
                const float4 hv = *(const float4*)&h_lds[r0 + ii][t];
                acc[ii] = fmaf(hv.x, w0, acc[ii]);
                acc[ii] = fmaf(hv.y, w1, acc[ii]);
                acc[ii] = fmaf(hv.z, w2, acc[ii]);
                acc[ii] = fmaf(hv.w, w3, acc[ii]);
            }
        }
        const float bk = mb1[k];
        #pragma unroll
        for (int ii = 0; ii < 4; ++ii) vv[ii] = acc[ii] + bk;
    }
    __syncthreads();   // publish u_lds (+ Asum)

    // ---- Phase 3: r[i_loc][k] = sum_j A[j][i_loc] * relu(u[j][k] + vv[i_loc]) ----
    {
        float racc[4];
        #pragma unroll
        for (int ii = 0; ii < 4; ++ii) racc[ii] = 0.0f;
        #pragma unroll 4
        for (int j = 0; j < DVAR; ++j) {
            const float uv = u_lds[j][k];
            const float4 a4 = *(const float4*)&A_lds[j][grp * 4];
            racc[0] = fmaf(fmaxf(uv + vv[0], 0.0f), a4.x, racc[0]);
            racc[1] = fmaf(fmaxf(uv + vv[1], 0.0f), a4.y, racc[1]);
            racc[2] = fmaf(fmaxf(uv + vv[2], 0.0f), a4.z, racc[2]);
            racc[3] = fmaf(fmaxf(uv + vv[3], 0.0f), a4.w, racc[3]);
        }
        #pragma unroll
        for (int ii = 0; ii < 4; ++ii) r_lds[grp * 4 + ii][k] = racc[ii];
    }
    __syncthreads();   // publish r_lds; u reads done -> rows 0..31 reusable as agg

    // ---- Phase 4: agg[ii][k] = r[ii] @ mw2[:,k] + Asum[ii]*mb2[k] (into u_lds rows 0..31) ----
    {
        float acc[4];
        #pragma unroll
        for (int ii = 0; ii < 4; ++ii) acc[ii] = 0.0f;
        #pragma unroll 4
        for (int t = 0; t < HDIM; t += 4) {
            const float w0 = mw2[(t + 0) * HDIM + k];
            const float w1 = mw2[(t + 1) * HDIM + k];
            const float w2 = mw2[(t + 2) * HDIM + k];
            const float w3 = mw2[(t + 3) * HDIM + k];
            #pragma unroll
            for (int ii = 0; ii < 4; ++ii) {
                const float4 rv = *(const float4*)&r_lds[grp * 4 + ii][t];
                acc[ii] = fmaf(rv.x, w0, acc[ii]);
                acc[ii] = fmaf(rv.y, w1, acc[ii]);
                acc[ii] = fmaf(rv.z, w2, acc[ii]);
                acc[ii] = fmaf(rv.w, w3, acc[ii]);
            }
        }
        const float b2 = mb2[k];
        #pragma unroll
        for (int ii = 0; ii < 4; ++ii)
            u_lds[grp * 4 + ii][k] = acc[ii] + Asum_lds[grp * 4 + ii] * b2;  // agg
    }
    __syncthreads();   // publish agg; r reads done -> reusable as z

    // ---- Phase 5: z[ii][k] = relu(h[i0+ii]@dw1[:H,k] + agg[ii]@dw1[H:,k] + db1[k]) ----
    {
        float acc[4];
        #pragma unroll
        for (int ii = 0; ii < 4; ++ii) acc[ii] = 0.0f;
        const int hrow0 = i0 + grp * 4;
        #pragma unroll 4
        for (int t = 0; t < HDIM; t += 4) {
            const float w0 = dw1[(t + 0) * HDIM + k];
            const float w1 = dw1[(t + 1) * HDIM + k];
            const float w2 = dw1[(t + 2) * HDIM + k];
            const float w3 = dw1[(t + 3) * HDIM + k];
            #pragma unroll
            for (int ii = 0; ii < 4; ++ii) {
                const float4 hv = *(const float4*)&h_lds[hrow0 + ii][t];
                acc[ii] = fmaf(hv.x, w0, acc[ii]);
                acc[ii] = fmaf(hv.y, w1, acc[ii]);
                acc[ii] = fmaf(hv.z, w2, acc[ii]);
                acc[ii] = fmaf(hv.w, w3, acc[ii]);
            }
        }
        #pragma unroll 4
        for (int t = 0; t < HDIM; t += 4) {
            const float w0 = dw1[(HDIM + t + 0) * HDIM + k];
            const float w1 = dw1[(HDIM + t + 1) * HDIM + k];
            const float w2 = dw1[(HDIM + t + 2) * HDIM + k];
            const float w3 = dw1[(HDIM + t + 3) * HDIM + k];
            #pragma unroll
            for (int ii = 0; ii < 4; ++ii) {
                const float4 av = *(const float4*)&u_lds[grp * 4 + ii][t];   // agg
                acc[ii] = fmaf(av.x, w0, acc[ii]);
                acc[ii] = fmaf(av.y, w1, acc[ii]);
                acc[ii] = fmaf(av.z, w2, acc[ii]);
                acc[ii] = fmaf(av.w, w3, acc[ii]);
            }
        }
        const float bk = db1[k];
        #pragma unroll
        for (int ii = 0; ii < 4; ++ii)
            r_lds[grp * 4 + ii][k] = fmaxf(acc[ii] + bk, 0.0f);   // z
    }
    __syncthreads();

    // ---- Phase 6: out[b][i0+row] = z[row] @ dw2 + db2 ----
    {
        const int row = tid >> 5;      // 0..31
        const int s   = tid & 31;
        float part = 0.0f;
        #pragma unroll
        for (int m = 0; m < 4; ++m) {
            const int kk = s + m * 32;
            part += r_lds[row][kk] * dw2[kk];
        }
        part += __shfl_xor(part, 1);
        part += __shfl_xor(part, 2);
        part += __shfl_xor(part, 4);
        part += __shfl_xor(part, 8);
        part += __shfl_xor(part, 16);
        if (s == 0) out[b * DVAR + i0 + row] = part + db2[0];
    }
}

extern "C" void kernel_launch(void* const* d_in, const int* in_sizes, int n_in,
                              void* d_out, int out_size, void* d_ws, size_t ws_size,
                              hipStream_t stream) {
    const float* X     = (const float*)d_in[0];
    const float* W     = (const float*)d_in[1];
    const float* enc_w = (const float*)d_in[2];
    const float* enc_b = (const float*)d_in[3];
    const float* mw1   = (const float*)d_in[4];
    const float* mb1   = (const float*)d_in[5];
    const float* mw2   = (const float*)d_in[6];
    const float* mb2   = (const float*)d_in[7];
    const float* dw1   = (const float*)d_in[8];
    const float* db1   = (const float*)d_in[9];
    const float* dw2   = (const float*)d_in[10];
    const float* db2   = (const float*)d_in[11];

    gnn_fused<<<dim3(BATCH * 2), dim3(NT), 0, stream>>>(
        X, W, enc_w, enc_b, mw1, mb1, mw2, mb2, dw1, db1, dw2, db2,
        (float*)d_out);
}

// Round 4
// 21.242 us; speedup vs baseline: 3.0016x; 2.2546x over previous
//
#include <hip/hip_runtime.h>

#define BATCH 128
#define DVAR  64
#define HDIM  128
#define NT    1024

typedef __attribute__((ext_vector_type(8))) __bf16 bf16x8;
typedef __attribute__((ext_vector_type(4))) float  f32x4;

__device__ __forceinline__ unsigned short f2bf(float f) {
    unsigned u = __float_as_uint(f);
    u += 0x7FFF + ((u >> 16) & 1);          // round-to-nearest-even
    return (unsigned short)(u >> 16);
}
__device__ __forceinline__ float bf2f(unsigned short b) {
    return __uint_as_float(((unsigned)b) << 16);
}

// ---------------- pre-pack: fp32 weights -> bf16 B-fragments in d_ws ----------------
// B-frag layout for mfma_f32_16x16x32_bf16: lane l supplies B[k=(l>>4)*8+e][col=l&15].
// pack[((n*KB + kb)*64 + l)*8 + e] = Wt[kb*32 + (l>>4)*8 + e][n*16 + (l&15)]
// sections: mw1 (K=256, KB=8) at 0; mw2 (K=128, KB=4) at 32768; dw1 (K=256, KB=8) at 49152.
__global__ void pack_w(const float* __restrict__ mw1, const float* __restrict__ mw2,
                       const float* __restrict__ dw1, unsigned short* __restrict__ ws) {
    int t = blockIdx.x * 256 + threadIdx.x;          // 0..10239
    const float* src; unsigned short* dst; int KB;
    if (t < 4096)      { src = mw1; dst = ws;         KB = 8; }
    else if (t < 6144) { src = mw2; dst = ws + 32768; KB = 4; t -= 4096; }
    else               { src = dw1; dst = ws + 49152; KB = 8; t -= 6144; }
    const int l  = t & 63, g = t >> 6;
    const int kb = g % KB, n = g / KB;
    const int k0  = kb * 32 + (l >> 4) * 8;
    const int col = n * 16 + (l & 15);
    unsigned short o[8];
    #pragma unroll
    for (int e = 0; e < 8; ++e) o[e] = f2bf(src[(k0 + e) * HDIM + col]);
    uint4 pk;
    unsigned short* pp = (unsigned short*)&pk;
    #pragma unroll
    for (int e = 0; e < 8; ++e) pp[e] = o[e];
    *(uint4*)(dst + (size_t)t * 8) = pk;             // coalesced 16B store
}

// ---------------- main fused kernel ----------------
// Grid 256 = (b = blockIdx>>1, i0 = (blockIdx&1)*32), 1024 threads = 16 waves.
__global__ __launch_bounds__(NT, 1) void gnn_fused(
    const float* __restrict__ X,  const float* __restrict__ W,
    const float* __restrict__ enc_w, const float* __restrict__ enc_b,
    const float* __restrict__ mb1, const float* __restrict__ mb2,
    const float* __restrict__ db1, const float* __restrict__ dw2,
    const float* __restrict__ db2,
    const unsigned short* __restrict__ ws,   // packed bf16 weights
    float* __restrict__ out)
{
    __shared__ unsigned short h_bf[DVAR * HDIM];   // 16 KB, XOR-swizzled rows
    __shared__ float          u_lds[DVAR * HDIM];  // 32 KB; reused as z after phase 4
    __shared__ float          v_lds[32 * HDIM];    // 16 KB
    __shared__ float          A_lds[DVAR][32];     // 8 KB
    __shared__ unsigned short r_bf[32 * HDIM];     // 8 KB, swizzled
    __shared__ unsigned short agg_bf[32 * HDIM];   // 8 KB, swizzled
    __shared__ float          Asum[32];

    const int tid  = threadIdx.x;
    const int b    = blockIdx.x >> 1;
    const int i0   = (blockIdx.x & 1) * 32;
    const int k    = tid & (HDIM - 1);
    const int g    = tid >> 7;          // 0..7, wave-uniform
    const int w    = tid >> 6;          // wave 0..15
    const int lane = tid & 63;
    const int lrow = lane & 15;
    const int lhi  = lane >> 4;

    const bf16x8* mw1p = (const bf16x8*)(const void*)(ws);
    const bf16x8* mw2p = (const bf16x8*)(const void*)(ws + 32768);
    const bf16x8* dw1p = (const bf16x8*)(const void*)(ws + 49152);

    // ---- P1: h = tanh(X*enc_w+enc_b) -> bf16 LDS (swizzled); stage A slab ----
    {
        const float ew = enc_w[k];
        const float eb = enc_b[k];
        #pragma unroll
        for (int m = 0; m < 8; ++m) {
            const int j = g + m * 8;                       // wave-uniform row
            const float hf = tanhf(X[b * DVAR + j] * ew + eb);
            h_bf[(j * HDIM + k) ^ ((j & 7) << 3)] = f2bf(hf);
        }
        #pragma unroll
        for (int m = 0; m < 2; ++m) {
            const int idx = tid + m * NT;                  // 0..2047
            const int j = idx >> 5, ii = idx & 31;
            A_lds[j][ii] = (j == i0 + ii) ? 0.0f : W[j * DVAR + i0 + ii];
        }
    }
    __syncthreads();
    if (tid < 32) {                                        // Asum[ii] = sum_j A[j,i]
        float s = 0.0f;
        for (int j = 0; j < DVAR; ++j) s += A_lds[j][tid];
        Asum[tid] = s;
    }

    // ---- P2 (MFMA): u[64][128] = h @ mw1[:H];  v[32][128] = h[i0:] @ mw1[H:] ----
    #pragma unroll
    for (int tt = 0; tt < 3; ++tt) {
        const int id = w + tt * 16;                        // 0..47
        const bool isU = id < 32;
        const int tv = isU ? id : id - 32;
        const int rt = isU ? (tv >> 3) : (tv >> 3);
        const int ct = tv & 7;
        const int Rsrc = isU ? rt * 16 : i0 + rt * 16;
        const int kbB0 = isU ? 0 : 4;
        f32x4 acc = {0.f, 0.f, 0.f, 0.f};
        #pragma unroll
        for (int kb = 0; kb < 4; ++kb) {
            const int row = Rsrc + lrow;
            const int eidx = (row * HDIM + kb * 32 + lhi * 8) ^ ((row & 7) << 3);
            bf16x8 a = *(const bf16x8*)(const void*)(h_bf + eidx);
            bf16x8 bb = mw1p[(ct * 8 + kbB0 + kb) * 64 + lane];
            acc = __builtin_amdgcn_mfma_f32_16x16x32_bf16(a, bb, acc, 0, 0, 0);
        }
        float* dst = isU ? u_lds : v_lds;
        const int orow0 = rt * 16 + lhi * 4;
        const int col = ct * 16 + lrow;
        #pragma unroll
        for (int r = 0; r < 4; ++r) dst[(orow0 + r) * HDIM + col] = acc[r];
    }
    __syncthreads();

    // ---- P3 (VALU): r[ii][k] = sum_j A[j][ii] * relu(u[j][k] + v[ii][k] + mb1[k]) ----
    {
        const float bk = mb1[k];
        float vvv[4];
        #pragma unroll
        for (int ii = 0; ii < 4; ++ii) vvv[ii] = v_lds[(g * 4 + ii) * HDIM + k] + bk;
        float racc[4] = {0.f, 0.f, 0.f, 0.f};
        #pragma unroll 4
        for (int j = 0; j < DVAR; ++j) {
            const float uv = u_lds[j * HDIM + k];
            const float4 a4 = *(const float4*)&A_lds[j][g * 4];   // wave-broadcast
            racc[0] = fmaf(fmaxf(uv + vvv[0], 0.f), a4.x, racc[0]);
            racc[1] = fmaf(fmaxf(uv + vvv[1], 0.f), a4.y, racc[1]);
            racc[2] = fmaf(fmaxf(uv + vvv[2], 0.f), a4.z, racc[2]);
            racc[3] = fmaf(fmaxf(uv + vvv[3], 0.f), a4.w, racc[3]);
        }
        #pragma unroll
        for (int ii = 0; ii < 4; ++ii) {
            const int row = g * 4 + ii;
            r_bf[(row * HDIM + k) ^ ((row & 7) << 3)] = f2bf(racc[ii]);
        }
    }
    __syncthreads();

    // ---- P4 (MFMA): agg[32][128] = r @ mw2 + Asum*mb2 -> bf16 LDS (swizzled) ----
    {
        const int rt = w >> 3, ct = w & 7;
        f32x4 acc = {0.f, 0.f, 0.f, 0.f};
        #pragma unroll
        for (int kb = 0; kb < 4; ++kb) {
            const int row = rt * 16 + lrow;
            const int eidx = (row * HDIM + kb * 32 + lhi * 8) ^ ((row & 7) << 3);
            bf16x8 a = *(const bf16x8*)(const void*)(r_bf + eidx);
            bf16x8 bb = mw2p[(ct * 4 + kb) * 64 + lane];
            acc = __builtin_amdgcn_mfma_f32_16x16x32_bf16(a, bb, acc, 0, 0, 0);
        }
        const int col = ct * 16 + lrow;
        const float m2 = mb2[col];
        #pragma unroll
        for (int r = 0; r < 4; ++r) {
            const int row = rt * 16 + lhi * 4 + r;
            const float val = acc[r] + Asum[row] * m2;
            agg_bf[(row * HDIM + col) ^ ((row & 7) << 3)] = f2bf(val);
        }
    }
    __syncthreads();

    // ---- P5 (MFMA): z = relu(h[i0:]@dw1[:H] + agg@dw1[H:] + db1) -> u_lds (reused) ----
    {
        const int rt = w >> 3, ct = w & 7;
        f32x4 acc = {0.f, 0.f, 0.f, 0.f};
        #pragma unroll
        for (int kb = 0; kb < 4; ++kb) {
            const int row = i0 + rt * 16 + lrow;
            const int eidx = (row * HDIM + kb * 32 + lhi * 8) ^ ((row & 7) << 3);
            bf16x8 a = *(const bf16x8*)(const void*)(h_bf + eidx);
            bf16x8 bb = dw1p[(ct * 8 + kb) * 64 + lane];
            acc = __builtin_amdgcn_mfma_f32_16x16x32_bf16(a, bb, acc, 0, 0, 0);
        }
        #pragma unroll
        for (int kb = 0; kb < 4; ++kb) {
            const int row = rt * 16 + lrow;
            const int eidx = (row * HDIM + kb * 32 + lhi * 8) ^ ((row & 7) << 3);
            bf16x8 a = *(const bf16x8*)(const void*)(agg_bf + eidx);
            bf16x8 bb = dw1p[(ct * 8 + 4 + kb) * 64 + lane];
            acc = __builtin_amdgcn_mfma_f32_16x16x32_bf16(a, bb, acc, 0, 0, 0);
        }
        const int col = ct * 16 + lrow;
        const float db = db1[col];
        #pragma unroll
        for (int r = 0; r < 4; ++r) {
            const int row = rt * 16 + lhi * 4 + r;
            u_lds[row * HDIM + col] = fmaxf(acc[r] + db, 0.f);   // z
        }
    }
    __syncthreads();

    // ---- P6: out[b][i0+row] = z[row] @ dw2 + db2 ----
    {
        const int row = tid >> 5;      // 0..31
        const int s   = tid & 31;
        float part = 0.0f;
        #pragma unroll
        for (int m = 0; m < 4; ++m) {
            const int kk = s + m * 32;
            part += u_lds[row * HDIM + kk] * dw2[kk];
        }
        part += __shfl_xor(part, 1);
        part += __shfl_xor(part, 2);
        part += __shfl_xor(part, 4);
        part += __shfl_xor(part, 8);
        part += __shfl_xor(part, 16);
        if (s == 0) out[b * DVAR + i0 + row] = part + db2[0];
    }
}

extern "C" void kernel_launch(void* const* d_in, const int* in_sizes, int n_in,
                              void* d_out, int out_size, void* d_ws, size_t ws_size,
                              hipStream_t stream) {
    const float* X     = (const float*)d_in[0];
    const float* W     = (const float*)d_in[1];
    const float* enc_w = (const float*)d_in[2];
    const float* enc_b = (const float*)d_in[3];
    const float* mw1   = (const float*)d_in[4];
    const float* mb1   = (const float*)d_in[5];
    const float* mw2   = (const float*)d_in[6];
    const float* mb2   = (const float*)d_in[7];
    const float* dw1   = (const float*)d_in[8];
    const float* db1   = (const float*)d_in[9];
    const float* dw2   = (const float*)d_in[10];
    const float* db2   = (const float*)d_in[11];
    unsigned short* wsp = (unsigned short*)d_ws;

    pack_w<<<dim3(40), dim3(256), 0, stream>>>(mw1, mw2, dw1, wsp);
    gnn_fused<<<dim3(BATCH * 2), dim3(NT), 0, stream>>>(
        X, W, enc_w, enc_b, mb1, mb2, db1, dw2, db2, wsp, (float*)d_out);
}